// Round 1
// baseline (333.725 us; speedup 1.0000x reference)
//
#include <hip/hip_runtime.h>

#define NTOT 50000
#define BB 16
#define N0 20000
#define N1 5000
#define N2 1000
#define E0C 320000
#define E1C 80000
#define E2C 16000

__global__ void zero_ints(int* __restrict__ p, int n) {
    int i = blockIdx.x * blockDim.x + threadIdx.x;
    if (i < n) p[i] = 0;
}

__global__ void hist_kernel(const int* __restrict__ dst, int ne, int* __restrict__ counts) {
    int i = blockIdx.x * blockDim.x + threadIdx.x;
    if (i < ne) atomicAdd(&counts[dst[i]], 1);
}

// single-block exclusive scan (Hillis-Steele over 1024-chunks)
__global__ void ex_scan(const int* __restrict__ counts, int n,
                        int* __restrict__ offs, int* __restrict__ cursor) {
    __shared__ int sd[1024];
    __shared__ int run;
    int t = threadIdx.x;
    if (t == 0) run = 0;
    __syncthreads();
    for (int base = 0; base < n; base += 1024) {
        int idx = base + t;
        int v = (idx < n) ? counts[idx] : 0;
        sd[t] = v;
        __syncthreads();
        int val = v;
        for (int o = 1; o < 1024; o <<= 1) {
            int add = (t >= o) ? sd[t - o] : 0;
            __syncthreads();
            val += add;
            sd[t] = val;
            __syncthreads();
        }
        int r = run;
        if (idx < n) {
            int ex = r + val - v;
            offs[idx] = ex;
            cursor[idx] = ex;
        }
        __syncthreads();
        if (t == 1023) run = r + val;
        __syncthreads();
    }
    if (t == 0) offs[n] = run;
}

__global__ void scatter_kernel(const int* __restrict__ src, const int* __restrict__ dst,
                               int ne, int* __restrict__ cursor, int* __restrict__ ssrc) {
    int i = blockIdx.x * blockDim.x + threadIdx.x;
    if (i < ne) {
        int d = dst[i];
        int pos = atomicAdd(&cursor[d], 1);
        ssrc[pos] = src[i];
    }
}

// xt0[n][b][c] = x[b][n_id[n]][c]   (node-major transpose-gather)
__global__ void gather_kernel(const float* __restrict__ x, const int* __restrict__ n_id,
                              float* __restrict__ xt0) {
    int idx = blockIdx.x * blockDim.x + threadIdx.x;
    if (idx >= N0 * 80) return;
    int n = idx / 80;
    int r = idx - n * 80;
    int b = r / 5;
    int c = r - b * 5;
    xt0[idx] = x[(size_t)b * (NTOT * 5) + (size_t)n_id[n] * 5 + c];
}

// SAGE layer 1: 5ch self-concat -> W1 (10x6) -> L2 normalize -> relu
// quarter-wave (16 lanes = batch) per dst node
__global__ __launch_bounds__(256) void sage1_kernel(
    const float* __restrict__ xt0, const int* __restrict__ offs, const int* __restrict__ ssrc,
    const float* __restrict__ W, const float* __restrict__ bias, float* __restrict__ xt1) {
    int gtid = blockIdx.x * blockDim.x + threadIdx.x;
    int wid = gtid >> 6;
    int lane = threadIdx.x & 63;
    int d = wid * 4 + (lane >> 4);
    int b = lane & 15;
    if (d >= N0) return;
    const float* ps = xt0 + (size_t)d * 80 + b * 5;
    float xs[5], a[5];
#pragma unroll
    for (int c = 0; c < 5; c++) { xs[c] = ps[c]; a[c] = xs[c]; }
    int e0 = offs[d], e1 = offs[d + 1];
    for (int e = e0; e < e1; e++) {
        int s = ssrc[e];
        const float* p = xt0 + (size_t)s * 80 + b * 5;
#pragma unroll
        for (int c = 0; c < 5; c++) a[c] += p[c];
    }
    float inv = 1.f / (float)(e1 - e0 + 1);
#pragma unroll
    for (int c = 0; c < 5; c++) a[c] *= inv;
    float o[6];
#pragma unroll
    for (int j = 0; j < 6; j++) {
        float acc = bias[j];
#pragma unroll
        for (int i = 0; i < 5; i++) acc += xs[i] * W[i * 6 + j];
#pragma unroll
        for (int i = 0; i < 5; i++) acc += a[i] * W[(5 + i) * 6 + j];
        o[j] = acc;
    }
    float nrm = 0.f;
#pragma unroll
    for (int j = 0; j < 6; j++) nrm += o[j] * o[j];
    float r = 1.f / fmaxf(sqrtf(nrm), 1e-12f);
    float* pd = xt1 + (size_t)d * 96 + b * 6;
#pragma unroll
    for (int j = 0; j < 6; j++) pd[j] = fmaxf(o[j] * r, 0.f);
}

// SAGE layer 2: 6ch self-concat -> W2 (12x36) -> L2 normalize -> relu
__global__ __launch_bounds__(256) void sage2_kernel(
    const float* __restrict__ xt1, const int* __restrict__ offs, const int* __restrict__ ssrc,
    const float* __restrict__ W, const float* __restrict__ bias, float* __restrict__ xt2) {
    int gtid = blockIdx.x * blockDim.x + threadIdx.x;
    int wid = gtid >> 6;
    int lane = threadIdx.x & 63;
    int d = wid * 4 + (lane >> 4);
    int b = lane & 15;
    if (d >= N0) return;
    const float* ps = xt1 + (size_t)d * 96 + b * 6;
    float xs[6], a[6];
#pragma unroll
    for (int c = 0; c < 6; c++) { xs[c] = ps[c]; a[c] = xs[c]; }
    int e0 = offs[d], e1 = offs[d + 1];
    for (int e = e0; e < e1; e++) {
        int s = ssrc[e];
        const float* p = xt1 + (size_t)s * 96 + b * 6;
#pragma unroll
        for (int c = 0; c < 6; c++) a[c] += p[c];
    }
    float inv = 1.f / (float)(e1 - e0 + 1);
#pragma unroll
    for (int c = 0; c < 6; c++) a[c] *= inv;
    float o[36];
#pragma unroll
    for (int j = 0; j < 36; j++) {
        float acc = bias[j];
#pragma unroll
        for (int i = 0; i < 6; i++) acc += xs[i] * W[i * 36 + j];
#pragma unroll
        for (int i = 0; i < 6; i++) acc += a[i] * W[(6 + i) * 36 + j];
        o[j] = acc;
    }
    float nrm = 0.f;
#pragma unroll
    for (int j = 0; j < 36; j++) nrm += o[j] * o[j];
    float r = 1.f / fmaxf(sqrtf(nrm), 1e-12f);
    float* pd = xt2 + (size_t)d * 576 + b * 36;
#pragma unroll
    for (int j = 0; j < 36; j++) pd[j] = fmaxf(o[j] * r, 0.f);
}

// SAGE layer 3: mean-agg (36ch) -> W3 (36x216) + b3, relu. Block per dst.
__global__ __launch_bounds__(256) void sage3_kernel(
    const float* __restrict__ xt2, const int* __restrict__ offs, const int* __restrict__ ssrc,
    const float* __restrict__ W3, const float* __restrict__ b3, float* __restrict__ xt3) {
    __shared__ float sW[36 * 216];
    __shared__ float sAgg[576];
    int d = blockIdx.x;
    int t = threadIdx.x;
    for (int i = t; i < 36 * 216; i += 256) sW[i] = W3[i];
    int e0 = offs[d], e1 = offs[d + 1];
    float a0 = 0.f, a1 = 0.f, a2 = 0.f;
    for (int e = e0; e < e1; e++) {
        int s = ssrc[e];
        const float* p = xt2 + (size_t)s * 576;
        a0 += p[t];
        a1 += p[t + 256];
        if (t < 64) a2 += p[t + 512];
    }
    float inv = 1.f / fmaxf((float)(e1 - e0), 1.f);
    sAgg[t] = a0 * inv;
    sAgg[t + 256] = a1 * inv;
    if (t < 64) sAgg[t + 512] = a2 * inv;
    __syncthreads();
    for (int i = t; i < 3456; i += 256) {
        int b = i / 216;
        int o = i - b * 216;
        float acc = b3[o];
#pragma unroll
        for (int c = 0; c < 36; c++) acc += sAgg[b * 36 + c] * sW[c * 216 + o];
        xt3[(size_t)d * 3456 + i] = fmaxf(acc, 0.f);
    }
}

// SAGE layer 4: mean-agg (216ch) -> W4 (216x2) + b4, no relu. Block per dst.
// Output layout: out[b][n][o] (B-major).
__global__ __launch_bounds__(256) void sage4_kernel(
    const float* __restrict__ xt3, const int* __restrict__ offs, const int* __restrict__ ssrc,
    const float* __restrict__ W4, const float* __restrict__ b4, float* __restrict__ out) {
    __shared__ float sAgg[3456];
    int d = blockIdx.x;
    int t = threadIdx.x;
    int e0 = offs[d], e1 = offs[d + 1];
    float a[14];
#pragma unroll
    for (int k = 0; k < 14; k++) a[k] = 0.f;
    for (int e = e0; e < e1; e++) {
        int s = ssrc[e];
        const float* p = xt3 + (size_t)s * 3456;
#pragma unroll
        for (int k = 0; k < 14; k++) {
            int i = t + 256 * k;
            if (i < 3456) a[k] += p[i];
        }
    }
    float inv = 1.f / fmaxf((float)(e1 - e0), 1.f);
#pragma unroll
    for (int k = 0; k < 14; k++) {
        int i = t + 256 * k;
        if (i < 3456) sAgg[i] = a[k] * inv;
    }
    __syncthreads();
    // 32 outputs (16 b x 2 o), 8 lanes each
    int g = t >> 3;       // 0..31
    int lane8 = t & 7;
    int b = g >> 1;
    int o = g & 1;
    float acc = 0.f;
    for (int c = lane8; c < 216; c += 8) acc += sAgg[b * 216 + c] * W4[c * 2 + o];
    acc += __shfl_down(acc, 4);
    acc += __shfl_down(acc, 2);
    acc += __shfl_down(acc, 1);
    if (lane8 == 0) out[b * (N2 * 2) + d * 2 + o] = acc + b4[o];
}

extern "C" void kernel_launch(void* const* d_in, const int* in_sizes, int n_in,
                              void* d_out, int out_size, void* d_ws, size_t ws_size,
                              hipStream_t stream) {
    const float* x   = (const float*)d_in[0];
    const int* n_id  = (const int*)d_in[1];
    const int* ei0   = (const int*)d_in[2];
    const int* ei1   = (const int*)d_in[3];
    const int* ei2   = (const int*)d_in[4];
    const float* W1  = (const float*)d_in[5];
    const float* b1  = (const float*)d_in[6];
    const float* W2  = (const float*)d_in[7];
    const float* b2  = (const float*)d_in[8];
    const float* W3  = (const float*)d_in[9];
    const float* b3  = (const float*)d_in[10];
    const float* W4  = (const float*)d_in[11];
    const float* b4  = (const float*)d_in[12];
    float* out = (float*)d_out;

    char* ws = (char*)d_ws;
    size_t off = 0;
    auto alloc = [&](size_t bytes) -> void* {
        void* p = ws + off;
        off += (bytes + 255) & ~(size_t)255;
        return p;
    };
    float* xt0 = (float*)alloc((size_t)N0 * 80 * 4);
    float* xt1 = (float*)alloc((size_t)N0 * 96 * 4);
    float* xt2 = (float*)alloc((size_t)N0 * 576 * 4);
    float* xt3 = (float*)alloc((size_t)N1 * 3456 * 4);
    int* counts = (int*)alloc(26000 * 4);  // [0:20000)=g0, [20000:25000)=g1, [25000:26000)=g2
    int* offs0 = (int*)alloc((N0 + 1) * 4);
    int* offs1 = (int*)alloc((N1 + 1) * 4);
    int* offs2 = (int*)alloc((N2 + 1) * 4);
    int* cur0 = (int*)alloc(N0 * 4);
    int* cur1 = (int*)alloc(N1 * 4);
    int* cur2 = (int*)alloc(N2 * 4);
    int* ss0 = (int*)alloc(E0C * 4);
    int* ss1 = (int*)alloc(E1C * 4);
    int* ss2 = (int*)alloc(E2C * 4);

    zero_ints<<<(26000 + 255) / 256, 256, 0, stream>>>(counts, 26000);
    hist_kernel<<<(E0C + 255) / 256, 256, 0, stream>>>(ei0 + E0C, E0C, counts);
    hist_kernel<<<(E1C + 255) / 256, 256, 0, stream>>>(ei1 + E1C, E1C, counts + 20000);
    hist_kernel<<<(E2C + 255) / 256, 256, 0, stream>>>(ei2 + E2C, E2C, counts + 25000);
    ex_scan<<<1, 1024, 0, stream>>>(counts, N0, offs0, cur0);
    ex_scan<<<1, 1024, 0, stream>>>(counts + 20000, N1, offs1, cur1);
    ex_scan<<<1, 1024, 0, stream>>>(counts + 25000, N2, offs2, cur2);
    scatter_kernel<<<(E0C + 255) / 256, 256, 0, stream>>>(ei0, ei0 + E0C, E0C, cur0, ss0);
    scatter_kernel<<<(E1C + 255) / 256, 256, 0, stream>>>(ei1, ei1 + E1C, E1C, cur1, ss1);
    scatter_kernel<<<(E2C + 255) / 256, 256, 0, stream>>>(ei2, ei2 + E2C, E2C, cur2, ss2);
    gather_kernel<<<(N0 * 80 + 255) / 256, 256, 0, stream>>>(x, n_id, xt0);
    sage1_kernel<<<1250, 256, 0, stream>>>(xt0, offs0, ss0, W1, b1, xt1);
    sage2_kernel<<<1250, 256, 0, stream>>>(xt1, offs0, ss0, W2, b2, xt2);
    sage3_kernel<<<N1, 256, 0, stream>>>(xt2, offs1, ss1, W3, b3, xt3);
    sage4_kernel<<<N2, 256, 0, stream>>>(xt3, offs2, ss2, W4, b4, out);
}

// Round 2
// 228.693 us; speedup vs baseline: 1.4593x; 1.4593x over previous
//
#include <hip/hip_runtime.h>

#define NTOT 50000
#define N0 20000
#define N1 5000
#define N2 1000
#define E0C 320000
#define E1C 80000
#define E2C 16000

__global__ void zero_ints(int* __restrict__ p, int n) {
    int i = blockIdx.x * blockDim.x + threadIdx.x;
    if (i < n) p[i] = 0;
}

// one fused histogram over all 3 graphs (counts: [0,N0)=g0, [N0,N0+N1)=g1, then g2)
__global__ void hist_all(const int* __restrict__ ei0, const int* __restrict__ ei1,
                         const int* __restrict__ ei2, int* __restrict__ counts) {
    int i = blockIdx.x * blockDim.x + threadIdx.x;
    if (i < E0C) {
        atomicAdd(&counts[ei0[E0C + i]], 1);
    } else if (i < E0C + E1C) {
        int j = i - E0C;
        atomicAdd(&counts[N0 + ei1[E1C + j]], 1);
    } else if (i < E0C + E1C + E2C) {
        int j = i - E0C - E1C;
        atomicAdd(&counts[N0 + N1 + ei2[E2C + j]], 1);
    }
}

// one block per graph; shuffle-based single-pass exclusive scan (no Hillis-Steele barriers)
__global__ __launch_bounds__(1024) void scan_all(
    const int* __restrict__ counts,
    int* __restrict__ offs0, int* __restrict__ cur0,
    int* __restrict__ offs1, int* __restrict__ cur1,
    int* __restrict__ offs2, int* __restrict__ cur2) {
    int g = blockIdx.x;
    int n = (g == 0) ? N0 : (g == 1) ? N1 : N2;
    const int* cnt = counts + ((g == 0) ? 0 : (g == 1) ? N0 : N0 + N1);
    int* offs = (g == 0) ? offs0 : (g == 1) ? offs1 : offs2;
    int* cur  = (g == 0) ? cur0  : (g == 1) ? cur1  : cur2;
    int t = threadIdx.x;
    int chunk = (n + 1023) >> 10;
    int lo = t * chunk;
    int hi = min(lo + chunk, n);
    int s = 0;
    for (int i = lo; i < hi; i++) s += cnt[i];
    int lane = t & 63, wid = t >> 6;
    int v = s;
    for (int d = 1; d < 64; d <<= 1) {
        int u = __shfl_up(v, d, 64);
        if (lane >= d) v += u;
    }
    __shared__ int wsum[16];
    __shared__ int woff[16];
    if (lane == 63) wsum[wid] = v;
    __syncthreads();
    if (t < 16) {
        int wv = wsum[t];
        int iv = wv;
        for (int d = 1; d < 16; d <<= 1) {
            int u = __shfl_up(iv, d, 64);
            if (t >= d) iv += u;
        }
        woff[t] = iv - wv;  // exclusive wave offset
    }
    __syncthreads();
    int run = woff[wid] + v - s;  // exclusive prefix at this thread's chunk start
    for (int i = lo; i < hi; i++) {
        offs[i] = run;
        cur[i] = run;
        run += cnt[i];
    }
    if (lo < n && hi == n) offs[n] = run;
}

__global__ void scatter_all(const int* __restrict__ ei0, const int* __restrict__ ei1,
                            const int* __restrict__ ei2,
                            int* __restrict__ cur0, int* __restrict__ cur1, int* __restrict__ cur2,
                            int* __restrict__ ss0, int* __restrict__ ss1, int* __restrict__ ss2) {
    int i = blockIdx.x * blockDim.x + threadIdx.x;
    if (i < E0C) {
        int d = ei0[E0C + i];
        int pos = atomicAdd(&cur0[d], 1);
        ss0[pos] = ei0[i];
    } else if (i < E0C + E1C) {
        int j = i - E0C;
        int d = ei1[E1C + j];
        int pos = atomicAdd(&cur1[d], 1);
        ss1[pos] = ei1[j];
    } else if (i < E0C + E1C + E2C) {
        int j = i - E0C - E1C;
        int d = ei2[E2C + j];
        int pos = atomicAdd(&cur2[d], 1);
        ss2[pos] = ei2[j];
    }
}

// xt0p[n][b][8] = x[b][n_id[n]][0..4] padded to 8 floats for b128 gathers downstream
__global__ void gather_kernel(const float* __restrict__ x, const int* __restrict__ n_id,
                              float* __restrict__ xt0p) {
    int idx = blockIdx.x * blockDim.x + threadIdx.x;
    if (idx >= N0 * 16) return;
    int n = idx >> 4, b = idx & 15;
    const float* p = x + (size_t)b * (NTOT * 5) + (size_t)n_id[n] * 5;
    float* q = xt0p + (size_t)n * 128 + b * 8;
    float4 v0 = {p[0], p[1], p[2], p[3]};
    float4 v1 = {p[4], 0.f, 0.f, 0.f};
    *(float4*)q = v0;
    *(float4*)(q + 4) = v1;
}

// SAGE layer 1: 5ch self-concat -> W1 (10x6) -> L2 normalize -> relu
// quarter-wave (16 lanes = batch) per dst node; padded rows (8 floats) -> b128 gathers
__global__ __launch_bounds__(256) void sage1_kernel(
    const float* __restrict__ xt0p, const int* __restrict__ offs, const int* __restrict__ ssrc,
    const float* __restrict__ W, const float* __restrict__ bias, float* __restrict__ xt1p) {
    int gtid = blockIdx.x * blockDim.x + threadIdx.x;
    int wid = gtid >> 6;
    int lane = threadIdx.x & 63;
    int d = wid * 4 + (lane >> 4);
    int b = lane & 15;
    if (d >= N0) return;
    const float* ps = xt0p + (size_t)d * 128 + b * 8;
    float4 x0 = *(const float4*)ps;
    float x4 = ps[4];
    float xs[5] = {x0.x, x0.y, x0.z, x0.w, x4};
    float a[5] = {xs[0], xs[1], xs[2], xs[3], xs[4]};
    int e0 = offs[d], e1 = offs[d + 1];
    for (int e = e0; e < e1; e++) {
        int s = ssrc[e];
        const float* p = xt0p + (size_t)s * 128 + b * 8;
        float4 v = *(const float4*)p;
        float v4 = p[4];
        a[0] += v.x; a[1] += v.y; a[2] += v.z; a[3] += v.w; a[4] += v4;
    }
    float inv = 1.f / (float)(e1 - e0 + 1);
#pragma unroll
    for (int c = 0; c < 5; c++) a[c] *= inv;
    float o[6];
#pragma unroll
    for (int j = 0; j < 6; j++) {
        float acc = bias[j];
#pragma unroll
        for (int i = 0; i < 5; i++) acc += xs[i] * W[i * 6 + j];
#pragma unroll
        for (int i = 0; i < 5; i++) acc += a[i] * W[(5 + i) * 6 + j];
        o[j] = acc;
    }
    float nrm = 0.f;
#pragma unroll
    for (int j = 0; j < 6; j++) nrm += o[j] * o[j];
    float r = 1.f / fmaxf(sqrtf(nrm), 1e-12f);
    float* pd = xt1p + (size_t)d * 128 + b * 8;
    float4 w0 = {fmaxf(o[0] * r, 0.f), fmaxf(o[1] * r, 0.f), fmaxf(o[2] * r, 0.f), fmaxf(o[3] * r, 0.f)};
    float4 w1 = {fmaxf(o[4] * r, 0.f), fmaxf(o[5] * r, 0.f), 0.f, 0.f};
    *(float4*)pd = w0;
    *(float4*)(pd + 4) = w1;
}

// SAGE layer 2: 6ch self-concat -> W2 (12x36) -> L2 normalize -> relu
__global__ __launch_bounds__(256) void sage2_kernel(
    const float* __restrict__ xt1p, const int* __restrict__ offs, const int* __restrict__ ssrc,
    const float* __restrict__ W, const float* __restrict__ bias, float* __restrict__ xt2) {
    int gtid = blockIdx.x * blockDim.x + threadIdx.x;
    int wid = gtid >> 6;
    int lane = threadIdx.x & 63;
    int d = wid * 4 + (lane >> 4);
    int b = lane & 15;
    if (d >= N0) return;
    const float* ps = xt1p + (size_t)d * 128 + b * 8;
    float4 u0 = *(const float4*)ps;
    float4 u1 = *(const float4*)(ps + 4);
    float xs[6] = {u0.x, u0.y, u0.z, u0.w, u1.x, u1.y};
    float a[6] = {xs[0], xs[1], xs[2], xs[3], xs[4], xs[5]};
    int e0 = offs[d], e1 = offs[d + 1];
    for (int e = e0; e < e1; e++) {
        int s = ssrc[e];
        const float* p = xt1p + (size_t)s * 128 + b * 8;
        float4 v0 = *(const float4*)p;
        float4 v1 = *(const float4*)(p + 4);
        a[0] += v0.x; a[1] += v0.y; a[2] += v0.z; a[3] += v0.w; a[4] += v1.x; a[5] += v1.y;
    }
    float inv = 1.f / (float)(e1 - e0 + 1);
#pragma unroll
    for (int c = 0; c < 6; c++) a[c] *= inv;
    float o[36];
#pragma unroll
    for (int j = 0; j < 36; j++) {
        float acc = bias[j];
#pragma unroll
        for (int i = 0; i < 6; i++) acc += xs[i] * W[i * 36 + j];
#pragma unroll
        for (int i = 0; i < 6; i++) acc += a[i] * W[(6 + i) * 36 + j];
        o[j] = acc;
    }
    float nrm = 0.f;
#pragma unroll
    for (int j = 0; j < 36; j++) nrm += o[j] * o[j];
    float r = 1.f / fmaxf(sqrtf(nrm), 1e-12f);
    float* pd = xt2 + (size_t)d * 576 + b * 36;
#pragma unroll
    for (int j = 0; j < 9; j++) {
        float4 w = {fmaxf(o[4 * j] * r, 0.f), fmaxf(o[4 * j + 1] * r, 0.f),
                    fmaxf(o[4 * j + 2] * r, 0.f), fmaxf(o[4 * j + 3] * r, 0.f)};
        *(float4*)(pd + 4 * j) = w;
    }
}

// SAGE layer 3 + fused W4 projection:
//   y[d][b][k] = relu(mean_agg(xt2)[d][b] @ W3 + b3) @ W4   (k=0..1)
// 4 dst per block (wave-per-dst). W3 staged in LDS once per block. Register-tiled
// matmul: thread owns 16 rows x 4 cols -> 64 acc; per k: 1 b128 W read (contiguous)
// + 4 broadcast b128 sAggT reads (conflict-free). xt3 never materialized.
__global__ __launch_bounds__(256, 4) void sage3_kernel(
    const float* __restrict__ xt2, const int* __restrict__ offs, const int* __restrict__ ssrc,
    const float* __restrict__ W3, const float* __restrict__ b3,
    const float* __restrict__ W4, float* __restrict__ y) {
    __shared__ float sW[36 * 216];      // 31104 B
    __shared__ float sAggT[36][68];     // transposed agg, 64 rows used, pad->68 (9792 B)
    int t = threadIdx.x;
    // stage W3 (float4)
    const float4* W3v = (const float4*)W3;
    float4* sWv = (float4*)sW;
    for (int i = t; i < 1944; i += 256) sWv[i] = W3v[i];

    int l = t >> 6;       // wave id = dst-local
    int q = t & 63;       // lane
    int l16 = l * 16;
    int d = blockIdx.x * 4 + l;
    int e0 = offs[d], e1 = offs[d + 1];

    // phase A: wave-cooperative mean aggregation of 576 floats (144 float4 chunks)
    float4 a0 = {0, 0, 0, 0}, a1 = {0, 0, 0, 0}, a2 = {0, 0, 0, 0};
    for (int e = e0; e < e1; e++) {
        int s = ssrc[e];
        const float4* p = (const float4*)(xt2 + (size_t)s * 576);
        float4 v0 = p[q];
        float4 v1 = p[q + 64];
        a0.x += v0.x; a0.y += v0.y; a0.z += v0.z; a0.w += v0.w;
        a1.x += v1.x; a1.y += v1.y; a1.z += v1.z; a1.w += v1.w;
        if (q < 16) {
            float4 v2 = p[q + 128];
            a2.x += v2.x; a2.y += v2.y; a2.z += v2.z; a2.w += v2.w;
        }
    }
    float inv = 1.f / fmaxf((float)(e1 - e0), 1.f);
    float av[12] = {a0.x, a0.y, a0.z, a0.w, a1.x, a1.y, a1.z, a1.w, a2.x, a2.y, a2.z, a2.w};
#pragma unroll
    for (int m = 0; m < 3; m++) {
        int chunk = q + 64 * m;
        if (chunk < 144) {
#pragma unroll
            for (int j = 0; j < 4; j++) {
                int el = chunk * 4 + j;      // = b*36 + c
                int bb = el / 36;
                int cc = el - bb * 36;
                sAggT[cc][l16 + bb] = av[m * 4 + j] * inv;
            }
        }
    }
    __syncthreads();

    // phase B: wave computes its dst's 16x216 = agg @ W3; thread = 4 cols (54 active lanes)
    int qc = (q < 54) ? q : 53;
    int o0 = qc * 4;
    float acc[16][4];
#pragma unroll
    for (int r = 0; r < 16; r++)
#pragma unroll
        for (int c = 0; c < 4; c++) acc[r][c] = 0.f;

#pragma unroll 4
    for (int k = 0; k < 36; k++) {
        float4 w = *(const float4*)&sW[k * 216 + o0];
        const float4* sap = (const float4*)&sAggT[k][l16];
        float4 s0 = sap[0], s1 = sap[1], s2 = sap[2], s3 = sap[3];
        float sar[16] = {s0.x, s0.y, s0.z, s0.w, s1.x, s1.y, s1.z, s1.w,
                         s2.x, s2.y, s2.z, s2.w, s3.x, s3.y, s3.z, s3.w};
#pragma unroll
        for (int r = 0; r < 16; r++) {
            acc[r][0] = fmaf(sar[r], w.x, acc[r][0]);
            acc[r][1] = fmaf(sar[r], w.y, acc[r][1]);
            acc[r][2] = fmaf(sar[r], w.z, acc[r][2]);
            acc[r][3] = fmaf(sar[r], w.w, acc[r][3]);
        }
    }

    // epilogue: +b3, relu, project by W4 (216->2) in-register
    float vals[32];
#pragma unroll
    for (int i = 0; i < 32; i++) vals[i] = 0.f;
    if (q < 54) {
        float4 bb = *(const float4*)&b3[o0];
        float4 w4a = *(const float4*)&W4[o0 * 2];       // (o0,k0),(o0,k1),(o0+1,k0),(o0+1,k1)
        float4 w4b = *(const float4*)&W4[o0 * 2 + 4];
        float w40[4] = {w4a.x, w4a.z, w4b.x, w4b.z};
        float w41[4] = {w4a.y, w4a.w, w4b.y, w4b.w};
        float bc[4] = {bb.x, bb.y, bb.z, bb.w};
#pragma unroll
        for (int r = 0; r < 16; r++) {
#pragma unroll
            for (int c = 0; c < 4; c++) {
                float vv = fmaxf(acc[r][c] + bc[c], 0.f);
                vals[r * 2 + 0] = fmaf(vv, w40[c], vals[r * 2 + 0]);
                vals[r * 2 + 1] = fmaf(vv, w41[c], vals[r * 2 + 1]);
            }
        }
    }
    // butterfly reduce-scatter over 64 lanes: 32 sums, each ends on one lane
#pragma unroll
    for (int i = 0; i < 5; i++) {
        int m = 1 << i;
        int half = 16 >> i;
        bool bit = (q >> i) & 1;
#pragma unroll
        for (int j = 0; j < 16; j++) {
            if (j < half) {
                float lo_ = vals[j], hi_ = vals[j + half];
                float send = bit ? lo_ : hi_;
                float recv = __shfl_xor(send, m, 64);
                vals[j] = (bit ? hi_ : lo_) + recv;
            }
        }
    }
    float tot = vals[0] + __shfl_xor(vals[0], 32, 64);
    if (q < 32) {
        int v = ((q & 1) << 4) | ((q & 2) << 2) | (q & 4) | ((q & 8) >> 2) | ((q & 16) >> 4);
        y[(size_t)d * 32 + v] = tot;   // v = b*2 + k
    }
}

// layer 4: mean-agg of projected y over edges2, + b4. out[b][n][k].
__global__ void final_kernel(const float* __restrict__ y, const int* __restrict__ offs,
                             const int* __restrict__ ssrc, const float* __restrict__ b4,
                             float* __restrict__ out) {
    int idx = blockIdx.x * blockDim.x + threadIdx.x;
    if (idx >= N2 * 16) return;
    int d = idx >> 4, b = idx & 15;
    int e0 = offs[d], e1 = offs[d + 1];
    float s0 = 0.f, s1 = 0.f;
    for (int e = e0; e < e1; e++) {
        int s = ssrc[e];
        const float2 v = *(const float2*)(y + (size_t)s * 32 + b * 2);
        s0 += v.x; s1 += v.y;
    }
    float inv = 1.f / fmaxf((float)(e1 - e0), 1.f);
    out[b * (N2 * 2) + d * 2 + 0] = s0 * inv + b4[0];
    out[b * (N2 * 2) + d * 2 + 1] = s1 * inv + b4[1];
}

extern "C" void kernel_launch(void* const* d_in, const int* in_sizes, int n_in,
                              void* d_out, int out_size, void* d_ws, size_t ws_size,
                              hipStream_t stream) {
    const float* x   = (const float*)d_in[0];
    const int* n_id  = (const int*)d_in[1];
    const int* ei0   = (const int*)d_in[2];
    const int* ei1   = (const int*)d_in[3];
    const int* ei2   = (const int*)d_in[4];
    const float* W1  = (const float*)d_in[5];
    const float* b1  = (const float*)d_in[6];
    const float* W2  = (const float*)d_in[7];
    const float* b2  = (const float*)d_in[8];
    const float* W3  = (const float*)d_in[9];
    const float* b3  = (const float*)d_in[10];
    const float* W4  = (const float*)d_in[11];
    const float* b4  = (const float*)d_in[12];
    float* out = (float*)d_out;

    char* ws = (char*)d_ws;
    size_t off = 0;
    auto alloc = [&](size_t bytes) -> void* {
        void* p = ws + off;
        off += (bytes + 255) & ~(size_t)255;
        return p;
    };
    float* xt0p = (float*)alloc((size_t)N0 * 128 * 4);
    float* xt1p = (float*)alloc((size_t)N0 * 128 * 4);
    float* xt2  = (float*)alloc((size_t)N0 * 576 * 4);
    float* yb   = (float*)alloc((size_t)N1 * 32 * 4);
    int* counts = (int*)alloc((N0 + N1 + N2) * 4);
    int* offs0 = (int*)alloc((N0 + 1) * 4);
    int* offs1 = (int*)alloc((N1 + 1) * 4);
    int* offs2 = (int*)alloc((N2 + 1) * 4);
    int* cur0 = (int*)alloc(N0 * 4);
    int* cur1 = (int*)alloc(N1 * 4);
    int* cur2 = (int*)alloc(N2 * 4);
    int* ss0 = (int*)alloc(E0C * 4);
    int* ss1 = (int*)alloc(E1C * 4);
    int* ss2 = (int*)alloc(E2C * 4);

    int etot = E0C + E1C + E2C;
    zero_ints<<<(N0 + N1 + N2 + 255) / 256, 256, 0, stream>>>(counts, N0 + N1 + N2);
    hist_all<<<(etot + 255) / 256, 256, 0, stream>>>(ei0, ei1, ei2, counts);
    scan_all<<<3, 1024, 0, stream>>>(counts, offs0, cur0, offs1, cur1, offs2, cur2);
    scatter_all<<<(etot + 255) / 256, 256, 0, stream>>>(ei0, ei1, ei2, cur0, cur1, cur2, ss0, ss1, ss2);
    gather_kernel<<<(N0 * 16 + 255) / 256, 256, 0, stream>>>(x, n_id, xt0p);
    sage1_kernel<<<1250, 256, 0, stream>>>(xt0p, offs0, ss0, W1, b1, xt1p);
    sage2_kernel<<<1250, 256, 0, stream>>>(xt1p, offs0, ss0, W2, b2, xt2);
    sage3_kernel<<<N1 / 4, 256, 0, stream>>>(xt2, offs1, ss1, W3, b3, W4, yb);
    final_kernel<<<(N2 * 16 + 255) / 256, 256, 0, stream>>>(yb, offs2, ss2, b4, out);
}